// Round 1
// baseline (1041.197 us; speedup 1.0000x reference)
//
#include <hip/hip_runtime.h>
#include <hip/hip_bf16.h>

#define NEG_SLOPE 0.2f
#define BN_EPS 1e-5f

// ---------------------------------------------------------------- CSR build
__global__ __launch_bounds__(256) void count_kernel(const int* __restrict__ dstl,
                                                    int E, int N, int* __restrict__ counts) {
    int i = blockIdx.x * 256 + threadIdx.x;
    if (i < E + N) {
        int d = (i < E) ? dstl[i] : (i - E);
        atomicAdd(&counts[d], 1);
    }
}

__global__ __launch_bounds__(1024) void scan_kernel(const int* __restrict__ counts,
                                                    int* __restrict__ indptr, int n) {
    __shared__ int sh[1024];
    __shared__ int s_carry;
    int t = threadIdx.x;
    if (t == 0) s_carry = 0;
    __syncthreads();
    for (int base = 0; base < n; base += 1024) {
        int i = base + t;
        int v = (i < n) ? counts[i] : 0;
        sh[t] = v;
        __syncthreads();
        #pragma unroll
        for (int off = 1; off < 1024; off <<= 1) {
            int add = (t >= off) ? sh[t - off] : 0;
            __syncthreads();
            sh[t] += add;
            __syncthreads();
        }
        int incl = sh[t] + s_carry;   // inclusive prefix + carry
        if (i < n) indptr[i + 1] = incl;
        __syncthreads();
        if (t == 1023) s_carry = incl;
        __syncthreads();
    }
    if (t == 0) indptr[0] = 0;
}

__global__ __launch_bounds__(256) void fill_kernel(const int* __restrict__ srcl,
                                                   const int* __restrict__ dstl,
                                                   int E, int N,
                                                   int* __restrict__ cursor,
                                                   int* __restrict__ esrc) {
    int i = blockIdx.x * 256 + threadIdx.x;
    if (i < E + N) {
        int s, d;
        if (i < E) { s = srcl[i]; d = dstl[i]; }
        else       { s = d = i - E; }
        int slot = atomicAdd(&cursor[d], 1);
        esrc[slot] = s;
    }
}

// ---------------------------------------------------------------- GEMM fp32
// C[N,M] = A[N,K] @ B[K,M] (+ bias). BM=BN=64, BK=16, 256 thr, 4x4/thread.
__global__ __launch_bounds__(256) void gemm_f32(const float* __restrict__ A,
                                                const float* __restrict__ B,
                                                const float* __restrict__ bias,
                                                float* __restrict__ C,
                                                int N, int K, int M) {
    __shared__ float As[16][64];
    __shared__ float Bs[16][64];
    int tid = threadIdx.x;
    int tx = tid & 15, ty = tid >> 4;
    int rowBase = blockIdx.y * 64;
    int colBase = blockIdx.x * 64;
    float acc[4][4] = {};
    for (int k0 = 0; k0 < K; k0 += 16) {
        {   // load A tile 64x16 (transposed into As[k][m])
            int r  = tid >> 2;
            int kc = (tid & 3) * 4;
            int gr = rowBase + r;
            float4 av = make_float4(0.f, 0.f, 0.f, 0.f);
            if (gr < N) av = *reinterpret_cast<const float4*>(&A[(size_t)gr * K + k0 + kc]);
            As[kc + 0][r] = av.x; As[kc + 1][r] = av.y;
            As[kc + 2][r] = av.z; As[kc + 3][r] = av.w;
        }
        {   // load B tile 16x64
            int kr = tid >> 4;
            int mc = (tid & 15) * 4;
            int gc = colBase + mc;
            float4 bv = make_float4(0.f, 0.f, 0.f, 0.f);
            if (gc < M) bv = *reinterpret_cast<const float4*>(&B[(size_t)(k0 + kr) * M + gc]);
            *reinterpret_cast<float4*>(&Bs[kr][mc]) = bv;
        }
        __syncthreads();
        #pragma unroll
        for (int k = 0; k < 16; k++) {
            float a[4], b[4];
            #pragma unroll
            for (int i = 0; i < 4; i++) a[i] = As[k][ty * 4 + i];
            #pragma unroll
            for (int j = 0; j < 4; j++) b[j] = Bs[k][tx * 4 + j];
            #pragma unroll
            for (int i = 0; i < 4; i++)
                #pragma unroll
                for (int j = 0; j < 4; j++)
                    acc[i][j] = fmaf(a[i], b[j], acc[i][j]);
        }
        __syncthreads();
    }
    #pragma unroll
    for (int i = 0; i < 4; i++) {
        int gr = rowBase + ty * 4 + i;
        if (gr >= N) continue;
        #pragma unroll
        for (int j = 0; j < 4; j++) {
            int gc = colBase + tx * 4 + j;
            if (gc >= M) continue;
            float v = acc[i][j];
            if (bias) v += bias[gc];
            C[(size_t)gr * M + gc] = v;
        }
    }
}

// ---------------------------------------------------------------- alpha (H=8,C=32)
__global__ __launch_bounds__(256) void alpha256(const float* __restrict__ h,
                                                const float* __restrict__ a_s,
                                                const float* __restrict__ a_d,
                                                float* __restrict__ as_out,
                                                float* __restrict__ ad_out, int N) {
    int n = blockIdx.x;
    int t = threadIdx.x;
    int head = t >> 5, c = t & 31;
    float hv = h[(size_t)n * 256 + t];
    float va = hv * a_s[t];
    float vd = hv * a_d[t];
    #pragma unroll
    for (int off = 16; off; off >>= 1) {
        va += __shfl_xor(va, off, 32);
        vd += __shfl_xor(vd, off, 32);
    }
    if (c == 0) {
        as_out[n * 8 + head] = va;
        ad_out[n * 8 + head] = vd;
    }
}

// ---------------------------------------------------------------- alpha (H=1,C=32)
__global__ __launch_bounds__(256) void alpha32(const float* __restrict__ h,
                                               const float* __restrict__ a_s,
                                               const float* __restrict__ a_d,
                                               float* __restrict__ as_out,
                                               float* __restrict__ ad_out, int N) {
    int t = threadIdx.x;
    int node = blockIdx.x * 8 + (t >> 5);
    int c = t & 31;
    if (node >= N) return;
    float hv = h[(size_t)node * 32 + c];
    float va = hv * a_s[c];
    float vd = hv * a_d[c];
    #pragma unroll
    for (int off = 16; off; off >>= 1) {
        va += __shfl_xor(va, off, 32);
        vd += __shfl_xor(vd, off, 32);
    }
    if (c == 0) {
        as_out[node] = va;
        ad_out[node] = vd;
    }
}

// ---------------------------------------------------------------- aggregation H=8,C=32
// MODE 1: out = elu(bn(agg + bias)) + skip ;  MODE 0: out = elu(bn(agg + bias))
template <int MODE>
__global__ __launch_bounds__(256) void agg256(const float* __restrict__ hfeat,
                                              const float* __restrict__ as,
                                              const float* __restrict__ ad,
                                              const int* __restrict__ indptr,
                                              const int* __restrict__ esrc,
                                              const float* __restrict__ bias,
                                              const float* __restrict__ bn_g,
                                              const float* __restrict__ bn_b,
                                              const float* __restrict__ bn_m,
                                              const float* __restrict__ bn_v,
                                              const float* skip,
                                              float* out, int N) {
    int n = blockIdx.x;
    if (n >= N) return;
    int t = threadIdx.x;
    int head = t >> 5;
    int start = indptr[n], end = indptr[n + 1];

    __shared__ float s_ad[8], s_m[8], s_il[8];
    __shared__ int   s_src[32];
    __shared__ float s_w[32][8];

    if (t < 8) s_ad[t] = ad[n * 8 + t];
    __syncthreads();

    if (t < 64) {   // stats by wave 0
        float mx[8];
        #pragma unroll
        for (int h = 0; h < 8; h++) mx[h] = -1e30f;
        for (int i = start + t; i < end; i += 64) {
            int s = esrc[i];
            #pragma unroll
            for (int h = 0; h < 8; h++) {
                float v = as[s * 8 + h] + s_ad[h];
                v = v > 0.f ? v : NEG_SLOPE * v;
                mx[h] = fmaxf(mx[h], v);
            }
        }
        #pragma unroll
        for (int h = 0; h < 8; h++)
            #pragma unroll
            for (int off = 32; off; off >>= 1)
                mx[h] = fmaxf(mx[h], __shfl_xor(mx[h], off));
        float sm[8];
        #pragma unroll
        for (int h = 0; h < 8; h++) sm[h] = 0.f;
        for (int i = start + t; i < end; i += 64) {
            int s = esrc[i];
            #pragma unroll
            for (int h = 0; h < 8; h++) {
                float v = as[s * 8 + h] + s_ad[h];
                v = v > 0.f ? v : NEG_SLOPE * v;
                sm[h] += __expf(v - mx[h]);
            }
        }
        #pragma unroll
        for (int h = 0; h < 8; h++)
            #pragma unroll
            for (int off = 32; off; off >>= 1)
                sm[h] += __shfl_xor(sm[h], off);
        if (t == 0) {
            #pragma unroll
            for (int h = 0; h < 8; h++) {
                s_m[h]  = mx[h];
                s_il[h] = 1.f / (sm[h] + 1e-16f);
            }
        }
    }
    __syncthreads();

    float acc = 0.f;
    for (int base = start; base < end; base += 32) {
        int ce = min(32, end - base);
        if (t < ce * 8) {
            int e = t >> 3, h = t & 7;
            int s = esrc[base + e];
            if (h == 0) s_src[e] = s;
            float v = as[s * 8 + h] + s_ad[h];
            v = v > 0.f ? v : NEG_SLOPE * v;
            s_w[e][h] = __expf(v - s_m[h]) * s_il[h];
        }
        __syncthreads();
        for (int e = 0; e < ce; e++)
            acc = fmaf(s_w[e][head], hfeat[(size_t)s_src[e] * 256 + t], acc);
        __syncthreads();
    }

    float val = acc + bias[t];
    val = (val - bn_m[t]) * rsqrtf(bn_v[t] + BN_EPS) * bn_g[t] + bn_b[t];
    val = val > 0.f ? val : (__expf(val) - 1.f);
    if (MODE == 1) val += skip[(size_t)n * 256 + t];
    out[(size_t)n * 256 + t] = val;
}

// ---------------------------------------------------------------- aggregation H=1,C=32
__global__ __launch_bounds__(64) void agg32(const float* __restrict__ h3,
                                            const float* __restrict__ as,
                                            const float* __restrict__ ad,
                                            const int* __restrict__ indptr,
                                            const int* __restrict__ esrc,
                                            const float* __restrict__ b3,
                                            const float* __restrict__ xs,
                                            float* __restrict__ out, int N) {
    int n = blockIdx.x;
    if (n >= N) return;
    int t = threadIdx.x;
    int c = t & 31, g = t >> 5;
    int start = indptr[n], end = indptr[n + 1];
    float adn = ad[n];

    float mx = -1e30f;
    for (int i = start + t; i < end; i += 64) {
        float v = as[esrc[i]] + adn;
        v = v > 0.f ? v : NEG_SLOPE * v;
        mx = fmaxf(mx, v);
    }
    #pragma unroll
    for (int off = 32; off; off >>= 1) mx = fmaxf(mx, __shfl_xor(mx, off));
    float sm = 0.f;
    for (int i = start + t; i < end; i += 64) {
        float v = as[esrc[i]] + adn;
        v = v > 0.f ? v : NEG_SLOPE * v;
        sm += __expf(v - mx);
    }
    #pragma unroll
    for (int off = 32; off; off >>= 1) sm += __shfl_xor(sm, off);
    float il = 1.f / (sm + 1e-16f);

    float acc = 0.f;
    for (int i = start + g; i < end; i += 2) {
        int s = esrc[i];
        float v = as[s] + adn;
        v = v > 0.f ? v : NEG_SLOPE * v;
        float w = __expf(v - mx) * il;
        acc = fmaf(w, h3[(size_t)s * 32 + c], acc);
    }
    acc += __shfl_xor(acc, 32);
    if (g == 0) out[(size_t)n * 32 + c] = acc + b3[c] + xs[(size_t)n * 32 + c];
}

// ---------------------------------------------------------------- launch
extern "C" void kernel_launch(void* const* d_in, const int* in_sizes, int n_in,
                              void* d_out, int out_size, void* d_ws, size_t ws_size,
                              hipStream_t stream) {
    const float* x      = (const float*)d_in[0];
    const int*   eidx   = (const int*)  d_in[1];
    const float* W1     = (const float*)d_in[2];
    const float* a_src1 = (const float*)d_in[3];
    const float* a_dst1 = (const float*)d_in[4];
    const float* b1     = (const float*)d_in[5];
    const float* bn1_g  = (const float*)d_in[6];
    const float* bn1_b  = (const float*)d_in[7];
    const float* bn1_m  = (const float*)d_in[8];
    const float* bn1_v  = (const float*)d_in[9];
    const float* W2     = (const float*)d_in[10];
    const float* a_src2 = (const float*)d_in[11];
    const float* a_dst2 = (const float*)d_in[12];
    const float* b2     = (const float*)d_in[13];
    const float* bn2_g  = (const float*)d_in[14];
    const float* bn2_b  = (const float*)d_in[15];
    const float* bn2_m  = (const float*)d_in[16];
    const float* bn2_v  = (const float*)d_in[17];
    const float* W3     = (const float*)d_in[18];
    const float* a_src3 = (const float*)d_in[19];
    const float* a_dst3 = (const float*)d_in[20];
    const float* b3     = (const float*)d_in[21];
    const float* Ws1    = (const float*)d_in[22];
    const float* bs1    = (const float*)d_in[23];
    const float* Ws2    = (const float*)d_in[24];
    const float* bs2    = (const float*)d_in[25];

    const int N = in_sizes[0] / 128;   // 50000
    const int E = in_sizes[1] / 2;     // 800000
    const int Etot = E + N;
    const int* srcl = eidx;
    const int* dstl = eidx + E;

    // workspace layout
    char* ws = (char*)d_ws;
    size_t off = 0;
    auto alloc = [&](size_t bytes) -> void* {
        void* p = ws + off;
        off += (bytes + 255) & ~(size_t)255;
        return p;
    };
    float* feat   = (float*)alloc((size_t)N * 256 * 4);  // x0, later layer-2 output
    float* hbuf   = (float*)alloc((size_t)N * 256 * 4);  // transformed features per layer
    float* h2buf  = (float*)alloc((size_t)N * 256 * 4);  // layer-1 output h
    float* xsbuf  = (float*)alloc((size_t)N * 32 * 4);
    float* h3buf  = (float*)alloc((size_t)N * 32 * 4);
    float* asb    = (float*)alloc((size_t)N * 8 * 4);
    float* adb    = (float*)alloc((size_t)N * 8 * 4);
    int* counts   = (int*)alloc((size_t)N * 4);
    int* cursor   = (int*)alloc((size_t)N * 4);
    int* indptr   = (int*)alloc((size_t)(N + 1) * 4);
    int* esrc     = (int*)alloc((size_t)Etot * 4);
    (void)ws_size; (void)n_in; (void)out_size;

    // ---- CSR by dst
    hipMemsetAsync(counts, 0, (size_t)N * 4, stream);
    int ceb = (Etot + 255) / 256;
    count_kernel<<<ceb, 256, 0, stream>>>(dstl, E, N, counts);
    scan_kernel<<<1, 1024, 0, stream>>>(counts, indptr, N);
    hipMemcpyAsync(cursor, indptr, (size_t)N * 4, hipMemcpyDeviceToDevice, stream);
    fill_kernel<<<ceb, 256, 0, stream>>>(srcl, dstl, E, N, cursor, esrc);

    dim3 g256((256 + 63) / 64, (N + 63) / 64);
    dim3 g32((32 + 63) / 64, (N + 63) / 64);

    // ---- layer 1
    gemm_f32<<<g256, 256, 0, stream>>>(x, Ws1, bs1, feat, N, 128, 256);     // x0
    gemm_f32<<<g256, 256, 0, stream>>>(x, W1, nullptr, hbuf, N, 128, 256);  // h1
    alpha256<<<N, 256, 0, stream>>>(hbuf, a_src1, a_dst1, asb, adb, N);
    agg256<1><<<N, 256, 0, stream>>>(hbuf, asb, adb, indptr, esrc, b1,
                                     bn1_g, bn1_b, bn1_m, bn1_v, feat, h2buf, N);

    // ---- layer 2
    gemm_f32<<<g32, 256, 0, stream>>>(h2buf, Ws2, bs2, xsbuf, N, 256, 32);  // xs
    gemm_f32<<<g256, 256, 0, stream>>>(h2buf, W2, nullptr, hbuf, N, 256, 256);
    alpha256<<<N, 256, 0, stream>>>(hbuf, a_src2, a_dst2, asb, adb, N);
    agg256<0><<<N, 256, 0, stream>>>(hbuf, asb, adb, indptr, esrc, b2,
                                     bn2_g, bn2_b, bn2_m, bn2_v, nullptr, feat, N);

    // ---- layer 3
    gemm_f32<<<g32, 256, 0, stream>>>(feat, W3, nullptr, h3buf, N, 256, 32);
    alpha32<<<(N + 7) / 8, 256, 0, stream>>>(h3buf, a_src3, a_dst3, asb, adb, N);
    agg32<<<N, 64, 0, stream>>>(h3buf, asb, adb, indptr, esrc, b3, xsbuf,
                                (float*)d_out, N);
}

// Round 2
// 932.353 us; speedup vs baseline: 1.1167x; 1.1167x over previous
//
#include <hip/hip_runtime.h>
#include <hip/hip_bf16.h>
#include <type_traits>

#define NEG_SLOPE 0.2f
#define BN_EPS 1e-5f

__device__ __forceinline__ float bf2f(unsigned short u) {
    union { unsigned int i; float f; } x;
    x.i = ((unsigned int)u) << 16;
    return x.f;
}
__device__ __forceinline__ unsigned short f2bf(float f) {
    __hip_bfloat16 b = __float2bfloat16(f);
    return *reinterpret_cast<unsigned short*>(&b);
}

// ---------------------------------------------------------------- CSR build
__global__ __launch_bounds__(256) void count_kernel(const int* __restrict__ dstl,
                                                    int E, int N, int* __restrict__ counts) {
    int i = blockIdx.x * 256 + threadIdx.x;
    if (i < E + N) {
        int d = (i < E) ? dstl[i] : (i - E);
        atomicAdd(&counts[d], 1);
    }
}

// block-level inclusive scan of 256 ints via shuffles
__device__ __forceinline__ int block_scan_incl(int v, int t) {
    int lane = t & 63, w = t >> 6;
    int sv = v;
    #pragma unroll
    for (int off = 1; off < 64; off <<= 1) {
        int u = __shfl_up(sv, off);
        if (lane >= off) sv += u;
    }
    __shared__ int ws[4];
    if (lane == 63) ws[w] = sv;
    __syncthreads();
    if (t == 0) {
        int a = 0;
        #pragma unroll
        for (int k = 0; k < 4; k++) { int x = ws[k]; ws[k] = a; a += x; }
    }
    __syncthreads();
    return sv + ws[w];
}

__global__ __launch_bounds__(256) void scan1(const int* __restrict__ counts,
                                             int* __restrict__ tmp,
                                             int* __restrict__ bsums, int n) {
    int t = threadIdx.x, i = blockIdx.x * 256 + t;
    int v = (i < n) ? counts[i] : 0;
    int incl = block_scan_incl(v, t);
    if (i < n) tmp[i] = incl;
    if (t == 255) bsums[blockIdx.x] = incl;
}

__global__ __launch_bounds__(256) void scan2(int* __restrict__ bsums, int nb) {
    int t = threadIdx.x;
    int v = (t < nb) ? bsums[t] : 0;
    int incl = block_scan_incl(v, t);
    if (t < nb) bsums[t] = incl - v;   // exclusive
}

__global__ __launch_bounds__(256) void scan3(const int* __restrict__ tmp,
                                             const int* __restrict__ bsums,
                                             const int* __restrict__ counts,
                                             int* __restrict__ indptr,
                                             int* __restrict__ cursor, int n) {
    int i = blockIdx.x * 256 + threadIdx.x;
    if (i < n) {
        int incl = tmp[i] + bsums[i >> 8];
        indptr[i + 1] = incl;
        cursor[i] = incl - counts[i];
        if (i == 0) indptr[0] = 0;
    }
}

__global__ __launch_bounds__(256) void fill_kernel(const int* __restrict__ srcl,
                                                   const int* __restrict__ dstl,
                                                   int E, int N,
                                                   int* __restrict__ cursor,
                                                   int* __restrict__ esrc) {
    int i = blockIdx.x * 256 + threadIdx.x;
    if (i < E + N) {
        int s, d;
        if (i < E) { s = srcl[i]; d = dstl[i]; }
        else       { s = d = i - E; }
        int slot = atomicAdd(&cursor[d], 1);
        esrc[slot] = s;
    }
}

// ---------------------------------------------------------------- GEMM fp32
// C[N,M] = A[N,K] @ B[K,M] (+ bias). BM=BN=64, BK=16, 256 thr, 4x4/thread.
template <typename OutT>
__global__ __launch_bounds__(256) void gemm_f32(const float* __restrict__ A,
                                                const float* __restrict__ B,
                                                const float* __restrict__ bias,
                                                OutT* __restrict__ C,
                                                int N, int K, int M) {
    __shared__ float As[16][64];
    __shared__ float Bs[16][64];
    int tid = threadIdx.x;
    int tx = tid & 15, ty = tid >> 4;
    int rowBase = blockIdx.y * 64;
    int colBase = blockIdx.x * 64;
    float acc[4][4] = {};
    for (int k0 = 0; k0 < K; k0 += 16) {
        {
            int r  = tid >> 2;
            int kc = (tid & 3) * 4;
            int gr = rowBase + r;
            float4 av = make_float4(0.f, 0.f, 0.f, 0.f);
            if (gr < N) av = *reinterpret_cast<const float4*>(&A[(size_t)gr * K + k0 + kc]);
            As[kc + 0][r] = av.x; As[kc + 1][r] = av.y;
            As[kc + 2][r] = av.z; As[kc + 3][r] = av.w;
        }
        {
            int kr = tid >> 4;
            int mc = (tid & 15) * 4;
            int gc = colBase + mc;
            float4 bv = make_float4(0.f, 0.f, 0.f, 0.f);
            if (gc < M) bv = *reinterpret_cast<const float4*>(&B[(size_t)(k0 + kr) * M + gc]);
            *reinterpret_cast<float4*>(&Bs[kr][mc]) = bv;
        }
        __syncthreads();
        #pragma unroll
        for (int k = 0; k < 16; k++) {
            float a[4], b[4];
            #pragma unroll
            for (int i = 0; i < 4; i++) a[i] = As[k][ty * 4 + i];
            #pragma unroll
            for (int j = 0; j < 4; j++) b[j] = Bs[k][tx * 4 + j];
            #pragma unroll
            for (int i = 0; i < 4; i++)
                #pragma unroll
                for (int j = 0; j < 4; j++)
                    acc[i][j] = fmaf(a[i], b[j], acc[i][j]);
        }
        __syncthreads();
    }
    #pragma unroll
    for (int i = 0; i < 4; i++) {
        int gr = rowBase + ty * 4 + i;
        if (gr >= N) continue;
        #pragma unroll
        for (int j = 0; j < 4; j++) {
            int gc = colBase + tx * 4 + j;
            if (gc >= M) continue;
            float v = acc[i][j];
            if (bias) v += bias[gc];
            if constexpr (sizeof(OutT) == 2) {
                C[(size_t)gr * M + gc] = (OutT)f2bf(v);
            } else {
                C[(size_t)gr * M + gc] = v;
            }
        }
    }
}

// ---------------------------------------------------------------- alpha (H=8,C=32) from bf16 h
__global__ __launch_bounds__(256) void alpha256(const unsigned short* __restrict__ h,
                                                const float* __restrict__ a_s,
                                                const float* __restrict__ a_d,
                                                float* __restrict__ as_out,
                                                float* __restrict__ ad_out, int N) {
    int n = blockIdx.x;
    int t = threadIdx.x;
    int head = t >> 5, c = t & 31;
    float hv = bf2f(h[(size_t)n * 256 + t]);
    float va = hv * a_s[t];
    float vd = hv * a_d[t];
    #pragma unroll
    for (int off = 16; off; off >>= 1) {
        va += __shfl_xor(va, off, 32);
        vd += __shfl_xor(vd, off, 32);
    }
    if (c == 0) {
        as_out[n * 8 + head] = va;
        ad_out[n * 8 + head] = vd;
    }
}

// ---------------------------------------------------------------- alpha (H=1,C=32)
__global__ __launch_bounds__(256) void alpha32(const float* __restrict__ h,
                                               const float* __restrict__ a_s,
                                               const float* __restrict__ a_d,
                                               float* __restrict__ as_out,
                                               float* __restrict__ ad_out, int N) {
    int t = threadIdx.x;
    int node = blockIdx.x * 8 + (t >> 5);
    int c = t & 31;
    if (node >= N) return;
    float hv = h[(size_t)node * 32 + c];
    float va = hv * a_s[c];
    float vd = hv * a_d[c];
    #pragma unroll
    for (int off = 16; off; off >>= 1) {
        va += __shfl_xor(va, off, 32);
        vd += __shfl_xor(vd, off, 32);
    }
    if (c == 0) {
        as_out[node] = va;
        ad_out[node] = vd;
    }
}

// ---------------------------------------------------------------- aggregation H=8,C=32
// wave w streams edges start+w, start+w+4, ...; lane owns 4 channels (float4);
// bf16 source rows (512B each). MODE 1: +skip.
template <int MODE>
__global__ __launch_bounds__(256) void agg256(const unsigned short* __restrict__ hfeat,
                                              const float* __restrict__ as,
                                              const float* __restrict__ ad,
                                              const int* __restrict__ indptr,
                                              const int* __restrict__ esrc,
                                              const float* __restrict__ bias,
                                              const float* __restrict__ bn_g,
                                              const float* __restrict__ bn_b,
                                              const float* __restrict__ bn_m,
                                              const float* __restrict__ bn_v,
                                              const float* skip,
                                              float* out, int N) {
    int n = blockIdx.x;
    if (n >= N) return;
    int t = threadIdx.x;
    int start = indptr[n], end = indptr[n + 1];

    __shared__ float s_ad[8], s_m[8], s_il[8];
    __shared__ float s_part[4][256];

    if (t < 8) s_ad[t] = ad[n * 8 + t];
    __syncthreads();

    if (t < 64) {   // softmax stats: wave 0, one edge per lane
        float mx[8], sm[8];
        #pragma unroll
        for (int h = 0; h < 8; h++) mx[h] = -3e38f;
        for (int i = start + t; i < end; i += 64) {
            int s = esrc[i];
            const float4* ap = reinterpret_cast<const float4*>(&as[s * 8]);
            float4 a0 = ap[0], a1 = ap[1];
            float e[8] = {a0.x, a0.y, a0.z, a0.w, a1.x, a1.y, a1.z, a1.w};
            #pragma unroll
            for (int h = 0; h < 8; h++) {
                float v = e[h] + s_ad[h];
                v = v > 0.f ? v : NEG_SLOPE * v;
                mx[h] = fmaxf(mx[h], v);
            }
        }
        #pragma unroll
        for (int h = 0; h < 8; h++)
            #pragma unroll
            for (int off = 32; off; off >>= 1)
                mx[h] = fmaxf(mx[h], __shfl_xor(mx[h], off));
        #pragma unroll
        for (int h = 0; h < 8; h++) sm[h] = 0.f;
        for (int i = start + t; i < end; i += 64) {
            int s = esrc[i];
            const float4* ap = reinterpret_cast<const float4*>(&as[s * 8]);
            float4 a0 = ap[0], a1 = ap[1];
            float e[8] = {a0.x, a0.y, a0.z, a0.w, a1.x, a1.y, a1.z, a1.w};
            #pragma unroll
            for (int h = 0; h < 8; h++) {
                float v = e[h] + s_ad[h];
                v = v > 0.f ? v : NEG_SLOPE * v;
                sm[h] += __expf(v - mx[h]);
            }
        }
        #pragma unroll
        for (int h = 0; h < 8; h++)
            #pragma unroll
            for (int off = 32; off; off >>= 1)
                sm[h] += __shfl_xor(sm[h], off);
        if (t == 0) {
            #pragma unroll
            for (int h = 0; h < 8; h++) {
                s_m[h]  = mx[h];
                s_il[h] = 1.f / (sm[h] + 1e-16f);
            }
        }
    }
    __syncthreads();

    int w = t >> 6, lane = t & 63;
    int head = lane >> 3;
    float madj = s_m[head], ilv = s_il[head], adv = s_ad[head];
    float4 acc = make_float4(0.f, 0.f, 0.f, 0.f);
    for (int i = start + w; i < end; i += 4) {
        int s = esrc[i];
        float v = as[s * 8 + head] + adv;
        v = v > 0.f ? v : NEG_SLOPE * v;
        float wgt = __expf(v - madj) * ilv;
        ushort4 hv = *reinterpret_cast<const ushort4*>(&hfeat[(size_t)s * 256 + lane * 4]);
        acc.x = fmaf(wgt, bf2f(hv.x), acc.x);
        acc.y = fmaf(wgt, bf2f(hv.y), acc.y);
        acc.z = fmaf(wgt, bf2f(hv.z), acc.z);
        acc.w = fmaf(wgt, bf2f(hv.w), acc.w);
    }
    *reinterpret_cast<float4*>(&s_part[w][lane * 4]) = acc;
    __syncthreads();

    float val = s_part[0][t] + s_part[1][t] + s_part[2][t] + s_part[3][t];
    val += bias[t];
    val = (val - bn_m[t]) * rsqrtf(bn_v[t] + BN_EPS) * bn_g[t] + bn_b[t];
    val = val > 0.f ? val : (__expf(val) - 1.f);
    if (MODE == 1) val += skip[(size_t)n * 256 + t];
    out[(size_t)n * 256 + t] = val;
}

// ---------------------------------------------------------------- aggregation H=1,C=32
// 8 edge streams per wave; lane l: stream l>>3, channels (l&7)*4 .. +3 (float4).
__global__ __launch_bounds__(64) void agg32(const float* __restrict__ h3,
                                            const float* __restrict__ as,
                                            const float* __restrict__ ad,
                                            const int* __restrict__ indptr,
                                            const int* __restrict__ esrc,
                                            const float* __restrict__ b3,
                                            const float* __restrict__ xs,
                                            float* __restrict__ out, int N) {
    int n = blockIdx.x;
    if (n >= N) return;
    int t = threadIdx.x;
    int start = indptr[n], end = indptr[n + 1];
    float adn = ad[n];

    float mx = -3e38f;
    for (int i = start + t; i < end; i += 64) {
        float v = as[esrc[i]] + adn;
        v = v > 0.f ? v : NEG_SLOPE * v;
        mx = fmaxf(mx, v);
    }
    #pragma unroll
    for (int off = 32; off; off >>= 1) mx = fmaxf(mx, __shfl_xor(mx, off));
    float sm = 0.f;
    for (int i = start + t; i < end; i += 64) {
        float v = as[esrc[i]] + adn;
        v = v > 0.f ? v : NEG_SLOPE * v;
        sm += __expf(v - mx);
    }
    #pragma unroll
    for (int off = 32; off; off >>= 1) sm += __shfl_xor(sm, off);
    float il = 1.f / (sm + 1e-16f);

    int estream = t >> 3, c4 = (t & 7) * 4;
    float4 acc = make_float4(0.f, 0.f, 0.f, 0.f);
    for (int i = start + estream; i < end; i += 8) {
        int s = esrc[i];
        float v = as[s] + adn;
        v = v > 0.f ? v : NEG_SLOPE * v;
        float wgt = __expf(v - mx) * il;
        float4 hv = *reinterpret_cast<const float4*>(&h3[(size_t)s * 32 + c4]);
        acc.x = fmaf(wgt, hv.x, acc.x);
        acc.y = fmaf(wgt, hv.y, acc.y);
        acc.z = fmaf(wgt, hv.z, acc.z);
        acc.w = fmaf(wgt, hv.w, acc.w);
    }
    #pragma unroll
    for (int mask = 8; mask < 64; mask <<= 1) {
        acc.x += __shfl_xor(acc.x, mask);
        acc.y += __shfl_xor(acc.y, mask);
        acc.z += __shfl_xor(acc.z, mask);
        acc.w += __shfl_xor(acc.w, mask);
    }
    if (t < 8) {
        float4 bv = *reinterpret_cast<const float4*>(&b3[c4]);
        float4 xv = *reinterpret_cast<const float4*>(&xs[(size_t)n * 32 + c4]);
        float4 o;
        o.x = acc.x + bv.x + xv.x;
        o.y = acc.y + bv.y + xv.y;
        o.z = acc.z + bv.z + xv.z;
        o.w = acc.w + bv.w + xv.w;
        *reinterpret_cast<float4*>(&out[(size_t)n * 32 + c4]) = o;
    }
}

// ---------------------------------------------------------------- launch
extern "C" void kernel_launch(void* const* d_in, const int* in_sizes, int n_in,
                              void* d_out, int out_size, void* d_ws, size_t ws_size,
                              hipStream_t stream) {
    const float* x      = (const float*)d_in[0];
    const int*   eidx   = (const int*)  d_in[1];
    const float* W1     = (const float*)d_in[2];
    const float* a_src1 = (const float*)d_in[3];
    const float* a_dst1 = (const float*)d_in[4];
    const float* b1     = (const float*)d_in[5];
    const float* bn1_g  = (const float*)d_in[6];
    const float* bn1_b  = (const float*)d_in[7];
    const float* bn1_m  = (const float*)d_in[8];
    const float* bn1_v  = (const float*)d_in[9];
    const float* W2     = (const float*)d_in[10];
    const float* a_src2 = (const float*)d_in[11];
    const float* a_dst2 = (const float*)d_in[12];
    const float* b2     = (const float*)d_in[13];
    const float* bn2_g  = (const float*)d_in[14];
    const float* bn2_b  = (const float*)d_in[15];
    const float* bn2_m  = (const float*)d_in[16];
    const float* bn2_v  = (const float*)d_in[17];
    const float* W3     = (const float*)d_in[18];
    const float* a_src3 = (const float*)d_in[19];
    const float* a_dst3 = (const float*)d_in[20];
    const float* b3     = (const float*)d_in[21];
    const float* Ws1    = (const float*)d_in[22];
    const float* bs1    = (const float*)d_in[23];
    const float* Ws2    = (const float*)d_in[24];
    const float* bs2    = (const float*)d_in[25];

    const int N = in_sizes[0] / 128;   // 50000
    const int E = in_sizes[1] / 2;     // 800000
    const int Etot = E + N;
    const int* srcl = eidx;
    const int* dstl = eidx + E;

    char* ws = (char*)d_ws;
    size_t off = 0;
    auto alloc = [&](size_t bytes) -> void* {
        void* p = ws + off;
        off += (bytes + 255) & ~(size_t)255;
        return p;
    };
    float* feat            = (float*)alloc((size_t)N * 256 * 4);  // x0 / layer-2 output
    unsigned short* hbuf   = (unsigned short*)alloc((size_t)N * 256 * 2);  // bf16 h per layer
    float* h2buf           = (float*)alloc((size_t)N * 256 * 4);  // layer-1 output
    float* xsbuf           = (float*)alloc((size_t)N * 32 * 4);
    float* h3buf           = (float*)alloc((size_t)N * 32 * 4);
    float* asb             = (float*)alloc((size_t)N * 8 * 4);
    float* adb             = (float*)alloc((size_t)N * 8 * 4);
    int* counts            = (int*)alloc((size_t)N * 4);
    int* cursor            = (int*)alloc((size_t)N * 4);
    int* indptr            = (int*)alloc((size_t)(N + 1) * 4);
    int* bsums             = (int*)alloc(256 * 4);
    int* esrc              = (int*)alloc((size_t)Etot * 4);
    (void)ws_size; (void)n_in; (void)out_size;

    // ---- CSR by dst
    hipMemsetAsync(counts, 0, (size_t)N * 4, stream);
    int ceb = (Etot + 255) / 256;
    int nb  = (N + 255) / 256;
    count_kernel<<<ceb, 256, 0, stream>>>(dstl, E, N, counts);
    scan1<<<nb, 256, 0, stream>>>(counts, cursor, bsums, N);      // cursor = tmp inclusive
    scan2<<<1, 256, 0, stream>>>(bsums, nb);
    scan3<<<nb, 256, 0, stream>>>(cursor, bsums, counts, indptr, cursor, N);
    fill_kernel<<<ceb, 256, 0, stream>>>(srcl, dstl, E, N, cursor, esrc);

    dim3 g256((256 + 63) / 64, (N + 63) / 64);
    dim3 g32((32 + 63) / 64, (N + 63) / 64);

    // ---- layer 1
    gemm_f32<float><<<g256, 256, 0, stream>>>(x, Ws1, bs1, feat, N, 128, 256);            // x0
    gemm_f32<unsigned short><<<g256, 256, 0, stream>>>(x, W1, nullptr, hbuf, N, 128, 256);
    alpha256<<<N, 256, 0, stream>>>(hbuf, a_src1, a_dst1, asb, adb, N);
    agg256<1><<<N, 256, 0, stream>>>(hbuf, asb, adb, indptr, esrc, b1,
                                     bn1_g, bn1_b, bn1_m, bn1_v, feat, h2buf, N);

    // ---- layer 2
    gemm_f32<float><<<g32, 256, 0, stream>>>(h2buf, Ws2, bs2, xsbuf, N, 256, 32);          // xs
    gemm_f32<unsigned short><<<g256, 256, 0, stream>>>(h2buf, W2, nullptr, hbuf, N, 256, 256);
    alpha256<<<N, 256, 0, stream>>>(hbuf, a_src2, a_dst2, asb, adb, N);
    agg256<0><<<N, 256, 0, stream>>>(hbuf, asb, adb, indptr, esrc, b2,
                                     bn2_g, bn2_b, bn2_m, bn2_v, nullptr, feat, N);

    // ---- layer 3
    gemm_f32<float><<<g32, 256, 0, stream>>>(feat, W3, nullptr, h3buf, N, 256, 32);
    alpha32<<<(N + 7) / 8, 256, 0, stream>>>(h3buf, a_src3, a_dst3, asb, adb, N);
    agg32<<<N, 64, 0, stream>>>(h3buf, asb, adb, indptr, esrc, b3, xsbuf,
                                (float*)d_out, N);
}

// Round 3
// 636.354 us; speedup vs baseline: 1.6362x; 1.4651x over previous
//
#include <hip/hip_runtime.h>
#include <hip/hip_bf16.h>

#define NEG_SLOPE 0.2f
#define BN_EPS 1e-5f

typedef __attribute__((ext_vector_type(8))) short bf16x8;
typedef __attribute__((ext_vector_type(4))) float f32x4;

__device__ __forceinline__ float bf2f(unsigned short u) {
    union { unsigned int i; float f; } x;
    x.i = ((unsigned int)u) << 16;
    return x.f;
}
__device__ __forceinline__ unsigned short f2bf(float f) {
    __hip_bfloat16 b = __float2bfloat16(f);
    return *reinterpret_cast<unsigned short*>(&b);
}
__device__ __forceinline__ float lrelu(float v) {
    return v > 0.f ? v : NEG_SLOPE * v;
}

// ---------------------------------------------------------------- CSR build
__global__ __launch_bounds__(256) void count_kernel(const int* __restrict__ dstl,
                                                    int E, int N, int* __restrict__ counts) {
    int i = blockIdx.x * 256 + threadIdx.x;
    if (i < E + N) {
        int d = (i < E) ? dstl[i] : (i - E);
        atomicAdd(&counts[d], 1);
    }
}

__device__ __forceinline__ int block_scan_incl(int v, int t) {
    int lane = t & 63, w = t >> 6;
    int sv = v;
    #pragma unroll
    for (int off = 1; off < 64; off <<= 1) {
        int u = __shfl_up(sv, off);
        if (lane >= off) sv += u;
    }
    __shared__ int ws[4];
    if (lane == 63) ws[w] = sv;
    __syncthreads();
    if (t == 0) {
        int a = 0;
        #pragma unroll
        for (int k = 0; k < 4; k++) { int x = ws[k]; ws[k] = a; a += x; }
    }
    __syncthreads();
    return sv + ws[w];
}

__global__ __launch_bounds__(256) void scan1(const int* __restrict__ counts,
                                             int* __restrict__ tmp,
                                             int* __restrict__ bsums, int n) {
    int t = threadIdx.x, i = blockIdx.x * 256 + t;
    int v = (i < n) ? counts[i] : 0;
    int incl = block_scan_incl(v, t);
    if (i < n) tmp[i] = incl;
    if (t == 255) bsums[blockIdx.x] = incl;
}

__global__ __launch_bounds__(256) void scan2(int* __restrict__ bsums, int nb) {
    int t = threadIdx.x;
    int v = (t < nb) ? bsums[t] : 0;
    int incl = block_scan_incl(v, t);
    if (t < nb) bsums[t] = incl - v;
}

__global__ __launch_bounds__(256) void scan3(const int* __restrict__ tmp,
                                             const int* __restrict__ bsums,
                                             const int* __restrict__ counts,
                                             int* __restrict__ indptr,
                                             int* __restrict__ cursor, int n) {
    int i = blockIdx.x * 256 + threadIdx.x;
    if (i < n) {
        int incl = tmp[i] + bsums[i >> 8];
        indptr[i + 1] = incl;
        cursor[i] = incl - counts[i];
        if (i == 0) indptr[0] = 0;
    }
}

__global__ __launch_bounds__(256) void fill_kernel(const int* __restrict__ srcl,
                                                   const int* __restrict__ dstl,
                                                   int E, int N,
                                                   int* __restrict__ cursor,
                                                   int* __restrict__ esrc) {
    int i = blockIdx.x * 256 + threadIdx.x;
    if (i < E + N) {
        int s, d;
        if (i < E) { s = srcl[i]; d = dstl[i]; }
        else       { s = d = i - E; }
        int slot = atomicAdd(&cursor[d], 1);
        esrc[slot] = s;
    }
}

// ---------------------------------------------------------------- converts
__global__ __launch_bounds__(256) void f32_to_bf16(const float* __restrict__ src,
                                                   unsigned short* __restrict__ dst, int n4) {
    int i = blockIdx.x * 256 + threadIdx.x;
    if (i < n4) {
        float4 v = reinterpret_cast<const float4*>(src)[i];
        ushort4 o;
        o.x = f2bf(v.x); o.y = f2bf(v.y); o.z = f2bf(v.z); o.w = f2bf(v.w);
        reinterpret_cast<ushort4*>(dst)[i] = o;
    }
}

// W[K x M] fp32 -> Wt[M x K] bf16
__global__ __launch_bounds__(256) void transpose_bf16(const float* __restrict__ src,
                                                      unsigned short* __restrict__ dst,
                                                      int K, int M) {
    int i = blockIdx.x * 256 + threadIdx.x;
    if (i < K * M) {
        int m = i / K, k = i - m * K;
        dst[i] = f2bf(src[(size_t)k * M + m]);
    }
}

// ---------------------------------------------------------------- bf16 MFMA GEMM
// C[M x NC] = A[M x K](bf16) @ B, with Bt[NC x K](bf16) = B^T. Block: 64 rows x NCT cols.
template <int NCT, typename OutT>
__global__ __launch_bounds__(256) void gemm_bf16(const unsigned short* __restrict__ A,
                                                 const unsigned short* __restrict__ Bt,
                                                 const float* __restrict__ bias,
                                                 OutT* __restrict__ C,
                                                 int M, int K, int NC) {
    constexpr int NF = NCT / 16;
    int t = threadIdx.x;
    int w = t >> 6, lane = t & 63;
    int l16 = lane & 15, quad = lane >> 4;
    int rowBase = blockIdx.y * 64 + w * 16;
    int colBase = blockIdx.x * NCT;

    f32x4 acc[NF];
    #pragma unroll
    for (int f = 0; f < NF; f++) acc[f] = (f32x4){0.f, 0.f, 0.f, 0.f};

    int arow = rowBase + l16;
    if (arow >= M) arow = M - 1;
    const unsigned short* aptr = A + (size_t)arow * K + quad * 8;

    for (int k0 = 0; k0 < K; k0 += 32) {
        bf16x8 af = *reinterpret_cast<const bf16x8*>(aptr + k0);
        #pragma unroll
        for (int f = 0; f < NF; f++) {
            int col = colBase + f * 16 + l16;
            bf16x8 bf = *reinterpret_cast<const bf16x8*>(&Bt[(size_t)col * K + k0 + quad * 8]);
            acc[f] = __builtin_amdgcn_mfma_f32_16x16x32_bf16(af, bf, acc[f], 0, 0, 0);
        }
    }

    #pragma unroll
    for (int f = 0; f < NF; f++) {
        int col = colBase + f * 16 + l16;
        float bv = bias ? bias[col] : 0.f;
        #pragma unroll
        for (int r = 0; r < 4; r++) {
            int row = rowBase + quad * 4 + r;
            if (row < M) {
                float v = acc[f][r] + bv;
                if constexpr (sizeof(OutT) == 2) C[(size_t)row * NC + col] = (OutT)f2bf(v);
                else                             C[(size_t)row * NC + col] = v;
            }
        }
    }
}

// ---------------------------------------------------------------- alpha (H=8,C=32), wave/node
__global__ __launch_bounds__(256) void alpha256(const unsigned short* __restrict__ h,
                                                const float* __restrict__ a_s,
                                                const float* __restrict__ a_d,
                                                float* __restrict__ as_out,
                                                float* __restrict__ ad_out, int N) {
    int t = threadIdx.x;
    int n = blockIdx.x * 4 + (t >> 6);
    if (n >= N) return;
    int lane = t & 63, lane4 = lane * 4;
    ushort4 hv = *reinterpret_cast<const ushort4*>(&h[(size_t)n * 256 + lane4]);
    float4 sv = *reinterpret_cast<const float4*>(&a_s[lane4]);
    float4 dv = *reinterpret_cast<const float4*>(&a_d[lane4]);
    float h0 = bf2f(hv.x), h1 = bf2f(hv.y), h2 = bf2f(hv.z), h3 = bf2f(hv.w);
    float va = h0 * sv.x + h1 * sv.y + h2 * sv.z + h3 * sv.w;
    float vd = h0 * dv.x + h1 * dv.y + h2 * dv.z + h3 * dv.w;
    #pragma unroll
    for (int off = 1; off < 8; off <<= 1) {
        va += __shfl_xor(va, off);
        vd += __shfl_xor(vd, off);
    }
    if ((lane & 7) == 0) {
        as_out[n * 8 + (lane >> 3)] = va;
        ad_out[n * 8 + (lane >> 3)] = vd;
    }
}

// ---------------------------------------------------------------- alpha (H=1,C=32), 8 nodes/wave
__global__ __launch_bounds__(256) void alpha32(const unsigned short* __restrict__ h,
                                               const float* __restrict__ a_s,
                                               const float* __restrict__ a_d,
                                               float* __restrict__ as_out,
                                               float* __restrict__ ad_out, int N) {
    int t = threadIdx.x;
    int lane = t & 63;
    int n = blockIdx.x * 32 + (t >> 6) * 8 + (lane >> 3);
    int c4 = (lane & 7) * 4;
    if (n >= N) return;
    ushort4 hv = *reinterpret_cast<const ushort4*>(&h[(size_t)n * 32 + c4]);
    float4 sv = *reinterpret_cast<const float4*>(&a_s[c4]);
    float4 dv = *reinterpret_cast<const float4*>(&a_d[c4]);
    float h0 = bf2f(hv.x), h1 = bf2f(hv.y), h2 = bf2f(hv.z), h3 = bf2f(hv.w);
    float va = h0 * sv.x + h1 * sv.y + h2 * sv.z + h3 * sv.w;
    float vd = h0 * dv.x + h1 * dv.y + h2 * dv.z + h3 * dv.w;
    #pragma unroll
    for (int off = 1; off < 8; off <<= 1) {
        va += __shfl_xor(va, off);
        vd += __shfl_xor(vd, off);
    }
    if ((lane & 7) == 0) {
        as_out[n] = va;
        ad_out[n] = vd;
    }
}

// ---------------------------------------------------------------- aggregation H=8,C=32
// One wave per node. Lane = e_sub*8 + h_sub for weights; lane owns channels lane*4..+3.
// Denominator applied post-hoc; no barriers, no LDS.
template <int MODE>
__global__ __launch_bounds__(256) void agg256(const unsigned short* __restrict__ hfeat,
                                              const float* __restrict__ as,
                                              const float* __restrict__ ad,
                                              const int* __restrict__ indptr,
                                              const int* __restrict__ esrc,
                                              const float* __restrict__ bias,
                                              const float* __restrict__ bn_g,
                                              const float* __restrict__ bn_b,
                                              const float* __restrict__ bn_m,
                                              const float* __restrict__ bn_v,
                                              const float* __restrict__ skip,
                                              unsigned short* __restrict__ out, int N) {
    int t = threadIdx.x;
    int n = blockIdx.x * 4 + (t >> 6);
    if (n >= N) return;
    int lane = t & 63;
    int e_sub = lane >> 3, h_sub = lane & 7;
    int ch_head = lane >> 3;           // head owning channels lane*4..+3
    int lane4 = lane * 4;
    int start = indptr[n], end = indptr[n + 1];
    int cnt = end - start;

    float adh = ad[n * 8 + h_sub];

    // ---- pass 1: per-head max
    float mxl = -3e38f;
    for (int i0 = start; i0 < end; i0 += 8) {
        int idx = i0 + e_sub;
        int s = esrc[idx < end ? idx : end - 1];
        float v = lrelu(as[s * 8 + h_sub] + adh);
        if (idx < end) mxl = fmaxf(mxl, v);
    }
    #pragma unroll
    for (int off = 8; off < 64; off <<= 1) mxl = fmaxf(mxl, __shfl_xor(mxl, off));

    // ---- main: unnormalized accumulate + denom
    float4 acc = make_float4(0.f, 0.f, 0.f, 0.f);
    float sm = 0.f;
    int nfull = cnt & ~7;
    for (int i0 = start; i0 < start + nfull; i0 += 8) {
        int s_l = esrc[i0 + e_sub];
        float v = lrelu(as[s_l * 8 + h_sub] + adh);
        float w8 = __expf(v - mxl);
        sm += w8;
        int se[8]; float we[8];
        #pragma unroll
        for (int e = 0; e < 8; e++) {
            se[e] = __shfl(s_l, e * 8);
            we[e] = __shfl(w8, e * 8 + ch_head);
        }
        ushort4 hv[8];
        #pragma unroll
        for (int e = 0; e < 8; e++)
            hv[e] = *reinterpret_cast<const ushort4*>(&hfeat[(size_t)se[e] * 256 + lane4]);
        #pragma unroll
        for (int e = 0; e < 8; e++) {
            acc.x = fmaf(we[e], bf2f(hv[e].x), acc.x);
            acc.y = fmaf(we[e], bf2f(hv[e].y), acc.y);
            acc.z = fmaf(we[e], bf2f(hv[e].z), acc.z);
            acc.w = fmaf(we[e], bf2f(hv[e].w), acc.w);
        }
    }
    int rem = cnt - nfull;
    if (rem) {
        int i0 = start + nfull;
        int idx = i0 + e_sub;
        int s_l = esrc[idx < end ? idx : end - 1];
        float v = lrelu(as[s_l * 8 + h_sub] + adh);
        float w8 = (idx < end) ? __expf(v - mxl) : 0.f;
        sm += w8;
        #pragma unroll
        for (int e = 0; e < 8; e++) {
            if (e < rem) {
                int se = __shfl(s_l, e * 8);
                float we = __shfl(w8, e * 8 + ch_head);
                ushort4 hv = *reinterpret_cast<const ushort4*>(&hfeat[(size_t)se * 256 + lane4]);
                acc.x = fmaf(we, bf2f(hv.x), acc.x);
                acc.y = fmaf(we, bf2f(hv.y), acc.y);
                acc.z = fmaf(we, bf2f(hv.z), acc.z);
                acc.w = fmaf(we, bf2f(hv.w), acc.w);
            }
        }
    }
    #pragma unroll
    for (int off = 8; off < 64; off <<= 1) sm += __shfl_xor(sm, off);
    float il = 1.f / (sm + 1e-16f);
    float il_c = __shfl(il, ch_head);

    // ---- epilogue
    float4 bv  = *reinterpret_cast<const float4*>(&bias[lane4]);
    float4 gv  = *reinterpret_cast<const float4*>(&bn_g[lane4]);
    float4 bbv = *reinterpret_cast<const float4*>(&bn_b[lane4]);
    float4 mv  = *reinterpret_cast<const float4*>(&bn_m[lane4]);
    float4 vv  = *reinterpret_cast<const float4*>(&bn_v[lane4]);
    float o[4] = {acc.x * il_c + bv.x, acc.y * il_c + bv.y,
                  acc.z * il_c + bv.z, acc.w * il_c + bv.w};
    float g[4] = {gv.x, gv.y, gv.z, gv.w}, bb[4] = {bbv.x, bbv.y, bbv.z, bbv.w};
    float m[4] = {mv.x, mv.y, mv.z, mv.w}, vr[4] = {vv.x, vv.y, vv.z, vv.w};
    float sk[4] = {0.f, 0.f, 0.f, 0.f};
    if (MODE == 1) {
        float4 s4 = *reinterpret_cast<const float4*>(&skip[(size_t)n * 256 + lane4]);
        sk[0] = s4.x; sk[1] = s4.y; sk[2] = s4.z; sk[3] = s4.w;
    }
    ushort4 res;
    unsigned short* rp = &res.x;
    #pragma unroll
    for (int j = 0; j < 4; j++) {
        float val = (o[j] - m[j]) * rsqrtf(vr[j] + BN_EPS) * g[j] + bb[j];
        val = val > 0.f ? val : (__expf(val) - 1.f);
        val += sk[j];
        rp[j] = f2bf(val);
    }
    *reinterpret_cast<ushort4*>(&out[(size_t)n * 256 + lane4]) = res;
}

// ---------------------------------------------------------------- aggregation H=1,C=32
// One wave per node; lane = e_sub*8 + c_sub; 8 edges in flight, no shuffle in hot loop.
__global__ __launch_bounds__(256) void agg32(const unsigned short* __restrict__ h3,
                                             const float* __restrict__ as,
                                             const float* __restrict__ ad,
                                             const int* __restrict__ indptr,
                                             const int* __restrict__ esrc,
                                             const float* __restrict__ b3,
                                             const float* __restrict__ xs,
                                             float* __restrict__ out, int N) {
    int t = threadIdx.x;
    int n = blockIdx.x * 4 + (t >> 6);
    if (n >= N) return;
    int lane = t & 63;
    int e_sub = lane >> 3, c4 = (lane & 7) * 4;
    int start = indptr[n], end = indptr[n + 1];
    float adn = ad[n];

    float mxl = -3e38f;
    for (int i0 = start; i0 < end; i0 += 8) {
        int idx = i0 + e_sub;
        float v = lrelu(as[esrc[idx < end ? idx : end - 1]] + adn);
        if (idx < end) mxl = fmaxf(mxl, v);
    }
    #pragma unroll
    for (int off = 8; off < 64; off <<= 1) mxl = fmaxf(mxl, __shfl_xor(mxl, off));

    float4 acc = make_float4(0.f, 0.f, 0.f, 0.f);
    float sm = 0.f;
    for (int i0 = start; i0 < end; i0 += 8) {
        int idx = i0 + e_sub;
        bool valid = idx < end;
        int s = esrc[valid ? idx : end - 1];
        float v = lrelu(as[s] + adn);
        float w = valid ? __expf(v - mxl) : 0.f;
        sm += w;
        ushort4 hv = *reinterpret_cast<const ushort4*>(&h3[(size_t)s * 32 + c4]);
        acc.x = fmaf(w, bf2f(hv.x), acc.x);
        acc.y = fmaf(w, bf2f(hv.y), acc.y);
        acc.z = fmaf(w, bf2f(hv.z), acc.z);
        acc.w = fmaf(w, bf2f(hv.w), acc.w);
    }
    #pragma unroll
    for (int off = 8; off < 64; off <<= 1) {
        sm    += __shfl_xor(sm, off);
        acc.x += __shfl_xor(acc.x, off);
        acc.y += __shfl_xor(acc.y, off);
        acc.z += __shfl_xor(acc.z, off);
        acc.w += __shfl_xor(acc.w, off);
    }
    if (e_sub == 0) {
        float il = 1.f / (sm + 1e-16f);
        float4 bv = *reinterpret_cast<const float4*>(&b3[c4]);
        float4 xv = *reinterpret_cast<const float4*>(&xs[(size_t)n * 32 + c4]);
        float4 o;
        o.x = acc.x * il + bv.x + xv.x;
        o.y = acc.y * il + bv.y + xv.y;
        o.z = acc.z * il + bv.z + xv.z;
        o.w = acc.w * il + bv.w + xv.w;
        *reinterpret_cast<float4*>(&out[(size_t)n * 32 + c4]) = o;
    }
}

// ---------------------------------------------------------------- launch
extern "C" void kernel_launch(void* const* d_in, const int* in_sizes, int n_in,
                              void* d_out, int out_size, void* d_ws, size_t ws_size,
                              hipStream_t stream) {
    const float* x      = (const float*)d_in[0];
    const int*   eidx   = (const int*)  d_in[1];
    const float* W1     = (const float*)d_in[2];
    const float* a_src1 = (const float*)d_in[3];
    const float* a_dst1 = (const float*)d_in[4];
    const float* b1     = (const float*)d_in[5];
    const float* bn1_g  = (const float*)d_in[6];
    const float* bn1_b  = (const float*)d_in[7];
    const float* bn1_m  = (const float*)d_in[8];
    const float* bn1_v  = (const float*)d_in[9];
    const float* W2     = (const float*)d_in[10];
    const float* a_src2 = (const float*)d_in[11];
    const float* a_dst2 = (const float*)d_in[12];
    const float* b2     = (const float*)d_in[13];
    const float* bn2_g  = (const float*)d_in[14];
    const float* bn2_b  = (const float*)d_in[15];
    const float* bn2_m  = (const float*)d_in[16];
    const float* bn2_v  = (const float*)d_in[17];
    const float* W3     = (const float*)d_in[18];
    const float* a_src3 = (const float*)d_in[19];
    const float* a_dst3 = (const float*)d_in[20];
    const float* b3     = (const float*)d_in[21];
    const float* Ws1    = (const float*)d_in[22];
    const float* bs1    = (const float*)d_in[23];
    const float* Ws2    = (const float*)d_in[24];
    const float* bs2    = (const float*)d_in[25];

    const int N = in_sizes[0] / 128;   // 50000
    const int E = in_sizes[1] / 2;     // 800000
    const int Etot = E + N;
    const int* srcl = eidx;
    const int* dstl = eidx + E;

    char* ws = (char*)d_ws;
    size_t off = 0;
    auto alloc = [&](size_t bytes) -> void* {
        void* p = ws + off;
        off += (bytes + 255) & ~(size_t)255;
        return p;
    };
    unsigned short* xb    = (unsigned short*)alloc((size_t)N * 128 * 2);
    float*          feat  = (float*)alloc((size_t)N * 256 * 4);          // x0 skip (fp32)
    unsigned short* hbuf  = (unsigned short*)alloc((size_t)N * 256 * 2); // gemm h output
    unsigned short* h2b   = (unsigned short*)alloc((size_t)N * 256 * 2); // layer-1 agg out
    unsigned short* featb = (unsigned short*)alloc((size_t)N * 256 * 2); // layer-2 agg out
    float*          xsbuf = (float*)alloc((size_t)N * 32 * 4);
    unsigned short* h3b   = (unsigned short*)alloc((size_t)N * 32 * 2);
    float*          asb   = (float*)alloc((size_t)N * 8 * 4);
    float*          adb   = (float*)alloc((size_t)N * 8 * 4);
    unsigned short* Ws1t  = (unsigned short*)alloc((size_t)128 * 256 * 2);
    unsigned short* W1t   = (unsigned short*)alloc((size_t)128 * 256 * 2);
    unsigned short* Ws2t  = (unsigned short*)alloc((size_t)256 * 32 * 2);
    unsigned short* W2t   = (unsigned short*)alloc((size_t)256 * 256 * 2);
    unsigned short* W3t   = (unsigned short*)alloc((size_t)256 * 32 * 2);
    int* counts = (int*)alloc((size_t)N * 4);
    int* cursor = (int*)alloc((size_t)N * 4);
    int* indptr = (int*)alloc((size_t)(N + 1) * 4);
    int* bsums  = (int*)alloc(256 * 4);
    int* esrc   = (int*)alloc((size_t)Etot * 4);
    (void)ws_size; (void)n_in; (void)out_size;

    // ---- CSR by dst
    hipMemsetAsync(counts, 0, (size_t)N * 4, stream);
    int ceb = (Etot + 255) / 256;
    int nb  = (N + 255) / 256;
    count_kernel<<<ceb, 256, 0, stream>>>(dstl, E, N, counts);
    scan1<<<nb, 256, 0, stream>>>(counts, cursor, bsums, N);
    scan2<<<1, 256, 0, stream>>>(bsums, nb);
    scan3<<<nb, 256, 0, stream>>>(cursor, bsums, counts, indptr, cursor, N);
    fill_kernel<<<ceb, 256, 0, stream>>>(srcl, dstl, E, N, cursor, esrc);

    // ---- convert inputs
    f32_to_bf16<<<((N * 128 / 4) + 255) / 256, 256, 0, stream>>>(x, xb, N * 128 / 4);
    transpose_bf16<<<(128 * 256 + 255) / 256, 256, 0, stream>>>(Ws1, Ws1t, 128, 256);
    transpose_bf16<<<(128 * 256 + 255) / 256, 256, 0, stream>>>(W1, W1t, 128, 256);
    transpose_bf16<<<(256 * 32 + 255) / 256, 256, 0, stream>>>(Ws2, Ws2t, 256, 32);
    transpose_bf16<<<(256 * 256 + 255) / 256, 256, 0, stream>>>(W2, W2t, 256, 256);
    transpose_bf16<<<(256 * 32 + 255) / 256, 256, 0, stream>>>(W3, W3t, 256, 32);

    int gy = (N + 63) / 64;
    int gn4 = (N + 3) / 4;

    // ---- layer 1
    gemm_bf16<64, float><<<dim3(4, gy), 256, 0, stream>>>(xb, Ws1t, bs1, feat, N, 128, 256);
    gemm_bf16<64, unsigned short><<<dim3(4, gy), 256, 0, stream>>>(xb, W1t, nullptr, hbuf, N, 128, 256);
    alpha256<<<gn4, 256, 0, stream>>>(hbuf, a_src1, a_dst1, asb, adb, N);
    agg256<1><<<gn4, 256, 0, stream>>>(hbuf, asb, adb, indptr, esrc, b1,
                                       bn1_g, bn1_b, bn1_m, bn1_v, feat, h2b, N);

    // ---- layer 2
    gemm_bf16<32, float><<<dim3(1, gy), 256, 0, stream>>>(h2b, Ws2t, bs2, xsbuf, N, 256, 32);
    gemm_bf16<64, unsigned short><<<dim3(4, gy), 256, 0, stream>>>(h2b, W2t, nullptr, hbuf, N, 256, 256);
    alpha256<<<gn4, 256, 0, stream>>>(hbuf, a_src2, a_dst2, asb, adb, N);
    agg256<0><<<gn4, 256, 0, stream>>>(hbuf, asb, adb, indptr, esrc, b2,
                                       bn2_g, bn2_b, bn2_m, bn2_v, nullptr, featb, N);

    // ---- layer 3
    gemm_bf16<32, unsigned short><<<dim3(1, gy), 256, 0, stream>>>(featb, W3t, nullptr, h3b, N, 256, 32);
    alpha32<<<(N + 31) / 32, 256, 0, stream>>>(h3b, a_src3, a_dst3, asb, adb, N);
    agg32<<<gn4, 256, 0, stream>>>(h3b, asb, adb, indptr, esrc, b3, xsbuf,
                                   (float*)d_out, N);
}